// Round 2
// baseline (125.237 us; speedup 1.0000x reference)
//
#include <hip/hip_runtime.h>

// FeatureScaling: per-feature piecewise-linear interpolation.
// inputs [B=8, N=2e6, F=3] f32 (f innermost), map_from/map_to [F=3, K=17] f32.
//
// R1 post-mortem: LDS-pipe-bound (19 ds_read/element). This version removes
// LDS entirely: each thread owns 12 consecutive elements (12 % 3 == 0), so
// the feature id of unrolled slot j is j%3 (compile-time). Interpolation is
// computed in clamp-sum form:
//   y = C + s0*min(x,xs1) + sum_{k=1..14} s_k*med3(x,xs_k,xs_{k+1}) + s15*max(x,xs15)
// with C = ys0 - sum_k s_k*xs_k.  All constants in registers, static indexing.

#define KBP 17
#define NSEG 16
#define NF 3

__device__ __forceinline__ float evalpl(float x, const float* xs, const float* sl, float C)
{
    float acc = fmaf(sl[0], fminf(x, xs[1]), C);
    acc = fmaf(sl[NSEG - 1], fmaxf(x, xs[NSEG - 1]), acc);
    #pragma unroll
    for (int k = 1; k < NSEG - 1; ++k) {
        float cl = fminf(fmaxf(x, xs[k]), xs[k + 1]);   // -> v_med3_f32
        acc = fmaf(sl[k], cl, acc);
    }
    return acc;
}

__global__ __launch_bounds__(256) void FeatureScaling_42752104464652_kernel(
    const float* __restrict__ in,
    const float* __restrict__ map_from,
    const float* __restrict__ map_to,
    float* __restrict__ out,
    long long n12 /* number of 12-element groups */, long long n_total)
{
    // ---- per-thread constant setup (uniform addresses -> scalar/L1 loads) ----
    float xs[NF][KBP];
    float sl[NF][NSEG];
    float C[NF];
    #pragma unroll
    for (int f = 0; f < NF; ++f) {
        #pragma unroll
        for (int k = 0; k < KBP; ++k) xs[f][k] = map_from[f * KBP + k];
        float ys0 = map_to[f * KBP + 0];
        float c = ys0;
        #pragma unroll
        for (int k = 0; k < NSEG; ++k) {
            float s = (map_to[f * KBP + k + 1] - map_to[f * KBP + k])
                      / (xs[f][k + 1] - xs[f][k]);
            sl[f][k] = s;
            c = fmaf(-s, xs[f][k], c);
        }
        C[f] = c;
    }

    const long long stride = (long long)gridDim.x * blockDim.x;
    long long i = (long long)blockIdx.x * blockDim.x + threadIdx.x;

    for (; i < n12; i += stride) {
        const float4* p = reinterpret_cast<const float4*>(in) + i * 3;
        float4 a = p[0];
        float4 b = p[1];
        float4 c4 = p[2];
        float v[12] = {a.x, a.y, a.z, a.w, b.x, b.y, b.z, b.w, c4.x, c4.y, c4.z, c4.w};
        float r[12];

        #pragma unroll
        for (int j = 0; j < 12; ++j) {
            const int f = j % 3;              // compile-time in unrolled loop
            r[j] = evalpl(v[j], xs[f], sl[f], C[f]);
        }

        float4* q = reinterpret_cast<float4*>(out) + i * 3;
        q[0] = make_float4(r[0], r[1], r[2], r[3]);
        q[1] = make_float4(r[4], r[5], r[6], r[7]);
        q[2] = make_float4(r[8], r[9], r[10], r[11]);
    }

    // Tail (n_total % 12 != 0) — never taken for 48M elements; global-only path.
    long long tail_start = n12 * 12;
    long long ti = tail_start + (long long)blockIdx.x * blockDim.x + threadIdx.x;
    for (; ti < n_total; ti += stride) {
        const float x = in[ti];
        const int f = (int)(ti % 3);
        const float* xg = map_from + f * KBP;
        const float* yg = map_to + f * KBP;
        int idx = 0;
        #pragma unroll
        for (int k = 1; k <= KBP - 2; ++k) idx += (x >= xg[k]) ? 1 : 0;
        const float x1 = xg[idx], x2 = xg[idx + 1];
        const float y1 = yg[idx], y2 = yg[idx + 1];
        out[ti] = y1 + (x - x1) * ((y2 - y1) / (x2 - x1));
    }
}

extern "C" void kernel_launch(void* const* d_in, const int* in_sizes, int n_in,
                              void* d_out, int out_size, void* d_ws, size_t ws_size,
                              hipStream_t stream) {
    const float* in       = (const float*)d_in[0];
    const float* map_from = (const float*)d_in[1];
    const float* map_to   = (const float*)d_in[2];
    float* out            = (float*)d_out;

    const long long n_total = (long long)in_sizes[0];  // 48,000,000
    const long long n12 = n_total / 12;                // 4,000,000

    const int block = 256;
    long long want = (n12 + block - 1) / block;
    int grid = (int)((want < 2048) ? (want > 0 ? want : 1) : 2048);

    FeatureScaling_42752104464652_kernel<<<grid, block, 0, stream>>>(
        in, map_from, map_to, out, n12, n_total);
}

// Round 3
// 87.924 us; speedup vs baseline: 1.4244x; 1.4244x over previous
//
#include <hip/hip_runtime.h>

// FeatureScaling: per-feature piecewise-linear interpolation.
// inputs [B=8, N=2e6, F=3] f32 (f innermost), map_from/map_to [F=3, K=17] f32.
//
// R1: LDS-pipe-bound (19 ds_read/elem -> 122us). R2: register tables but
// per-lane stride-48B float4 loads broke coalescing (153us).
// R3: coalesced float4 (lane i -> float4 i) + register tables. Per-thread
// feature phase m=(blockIdx+tid)%3 is invariant across grid-stride iters
// (stride % 3 == 0), so tables are rotated ONCE into registers; every
// unrolled slot (c,j) uses compile-time rotated index (c+j)%3.
//
// Interpolation in clamp-sum form (validated in R2, absmax 0.0039):
//   y = C + s0*min(x,xs1) + sum_{k=1..14} s_k*med3(x,xs_k,xs_{k+1}) + s15*max(x,xs15)

#define KBP 17
#define NSEG 16
#define NF 3
#define CHUNKS 4   // float4s per thread per iteration, spaced blockDim apart

// m==0 ? a : m==1 ? b : c   (2x v_cndmask)
__device__ __forceinline__ float sel3(float a, float b, float c, int m) {
    float r = (m == 1) ? b : a;
    return (m == 2) ? c : r;
}

// rx[0..14] = xs[1..15]; sl[0..15] slopes; C = ys0 - sum sl_k*xs_k
__device__ __forceinline__ float evalpl(float x, const float* rx, const float* sl, float C)
{
    float acc = fmaf(sl[0], fminf(x, rx[0]), C);
    acc = fmaf(sl[NSEG - 1], fmaxf(x, rx[NSEG - 2]), acc);
    #pragma unroll
    for (int k = 1; k < NSEG - 1; ++k) {
        float cl = fminf(fmaxf(x, rx[k - 1]), rx[k]);   // -> v_med3_f32
        acc = fmaf(sl[k], cl, acc);
    }
    return acc;
}

__global__ __launch_bounds__(256) void FeatureScaling_42752104464652_kernel(
    const float* __restrict__ in,
    const float* __restrict__ map_from,
    const float* __restrict__ map_to,
    float* __restrict__ out,
    long long n4 /* total float4 count */)
{
    // ---- raw tables (uniform addresses -> s_load path) ----
    float bx[NF][KBP];
    float bs[NF][NSEG];
    float bc[NF];
    #pragma unroll
    for (int f = 0; f < NF; ++f) {
        #pragma unroll
        for (int k = 0; k < KBP; ++k) bx[f][k] = map_from[f * KBP + k];
        float c = map_to[f * KBP + 0];
        #pragma unroll
        for (int k = 0; k < NSEG; ++k) {
            float s = (map_to[f * KBP + k + 1] - map_to[f * KBP + k])
                      / (bx[f][k + 1] - bx[f][k]);
            bs[f][k] = s;
            c = fmaf(-s, bx[f][k], c);
        }
        bc[f] = c;
    }

    const int t = threadIdx.x;
    // element e = 4*i + j has f = (i + j) % 3 (4 == 1 mod 3).
    // float4 index i_c = blockIdx*1024 + c*256 + t (+ iter*stride4), and
    // 1024 == 1, 256 == 1 (mod 3), stride4 == 0 (mod 3) =>
    // i_c == (blockIdx + t + c) (mod 3). Phase m fixed per thread:
    const int m = (int)((blockIdx.x + t) % 3);

    // ---- one-time rotation: rot[r] = table[(m + r) % 3] ----
    float rx[NF][NSEG - 1];   // xs[1..15] per rotated set
    float rs[NF][NSEG];
    float rC[NF];
    #pragma unroll
    for (int r = 0; r < NF; ++r) {
        const int a0 = r, a1 = (r + 1) % 3, a2 = (r + 2) % 3;
        #pragma unroll
        for (int k = 0; k < NSEG - 1; ++k)
            rx[r][k] = sel3(bx[a0][k + 1], bx[a1][k + 1], bx[a2][k + 1], m);
        #pragma unroll
        for (int k = 0; k < NSEG; ++k)
            rs[r][k] = sel3(bs[a0][k], bs[a1][k], bs[a2][k], m);
        rC[r] = sel3(bc[a0], bc[a1], bc[a2], m);
    }

    const float4* __restrict__ in4 = reinterpret_cast<const float4*>(in);
    float4* __restrict__ out4 = reinterpret_cast<float4*>(out);

    const long long stride4 = (long long)gridDim.x * blockDim.x * CHUNKS;  // % 3 == 0
    long long b = (long long)blockIdx.x * (blockDim.x * CHUNKS) + t;

    for (; b < n4; b += stride4) {
        float4 v[CHUNKS];
        #pragma unroll
        for (int c = 0; c < CHUNKS; ++c) {
            long long ic = b + c * 256;
            if (ic < n4) v[c] = in4[ic];
        }
        float4 rres[CHUNKS];
        #pragma unroll
        for (int c = 0; c < CHUNKS; ++c) {
            float xv[4] = {v[c].x, v[c].y, v[c].z, v[c].w};
            float rv[4];
            #pragma unroll
            for (int j = 0; j < 4; ++j) {
                const int r = (c + j) % 3;   // compile-time rotated index
                rv[j] = evalpl(xv[j], rx[r], rs[r], rC[r]);
            }
            rres[c] = make_float4(rv[0], rv[1], rv[2], rv[3]);
        }
        #pragma unroll
        for (int c = 0; c < CHUNKS; ++c) {
            long long ic = b + c * 256;
            if (ic < n4) out4[ic] = rres[c];
        }
    }
}

extern "C" void kernel_launch(void* const* d_in, const int* in_sizes, int n_in,
                              void* d_out, int out_size, void* d_ws, size_t ws_size,
                              hipStream_t stream) {
    const float* in       = (const float*)d_in[0];
    const float* map_from = (const float*)d_in[1];
    const float* map_to   = (const float*)d_in[2];
    float* out            = (float*)d_out;

    const long long n_total = (long long)in_sizes[0];  // 48,000,000 (divisible by 4)
    const long long n4 = n_total / 4;                  // 12,000,000

    const int block = 256;
    // grid must be a multiple of 3 so stride4 % 3 == 0 (phase invariance)
    int grid = 1023;  // 3 * 341; coverage/sweep = 1023*256*4 float4s, ~11.5 sweeps
    long long want = (n4 + (long long)block * CHUNKS - 1) / ((long long)block * CHUNKS);
    if (want < grid) grid = (int)((want + 2) / 3 * 3);  // round up to multiple of 3
    if (grid < 3) grid = 3;

    FeatureScaling_42752104464652_kernel<<<grid, block, 0, stream>>>(
        in, map_from, map_to, out, n4);
}

// Round 5
// 78.331 us; speedup vs baseline: 1.5988x; 1.1225x over previous
//
#include <hip/hip_runtime.h>

// FeatureScaling: per-feature piecewise-linear interpolation.
// inputs [B=8, N=2e6, F=3] f32 (f innermost), map_from/map_to [F=3, K=17] f32.
//
// R1: LDS-pipe-bound (19 ds_read/elem, 122us). R2: per-lane stride-48B loads
// broke coalescing (153us). R3: coalesced + register tables, but 96 per-lane
// table values -> sel3 rematerialization -> 3.5x VALU (88us).
// R4: affine specialization — correct idea, but FORGOT THE STORE in the fast
// path (out4[ic] = o missing). R5 = R4 + the store.
//
// Runtime-verified AFFINE specialization: if for every feature the
// (map_from, map_to) breakpoints are colinear (and map_from monotone), the
// piecewise-linear map — including both extrapolation ends — is exactly
// y = S_f*x + B_f. Wave-uniform check; fast path is 1 FMA/element with 6
// per-lane rotated constants; generic LDS-searchsorted fallback otherwise.

#define KBP 17
#define NF 3
#define CHUNKS 5   // float4s per thread, spaced blockDim apart; 12e6 = 9375*1280

// m==0 ? a : m==1 ? b : c   (2x v_cndmask)
__device__ __forceinline__ float sel3(float a, float b, float c, int m) {
    float r = (m == 1) ? b : a;
    return (m == 2) ? c : r;
}

__global__ __launch_bounds__(256) void FeatureScaling_42752104464652_kernel(
    const float* __restrict__ in,
    const float* __restrict__ map_from,
    const float* __restrict__ map_to,
    float* __restrict__ out,
    long long n4, long long n_total)
{
    __shared__ float s_from[NF * KBP];
    __shared__ float s_to[NF * KBP];
    const int t = threadIdx.x;
    if (t < NF * KBP) {
        s_from[t] = map_from[t];
        s_to[t]   = map_to[t];
    }
    __syncthreads();

    // ---- wave-uniform affine (colinearity) check + coefficients ----
    float S[NF], Bv[NF];
    bool affine = true;
    #pragma unroll
    for (int f = 0; f < NF; ++f) {
        const float x0 = map_from[f * KBP + 0];
        const float xK = map_from[f * KBP + KBP - 1];
        const float y0 = map_to[f * KBP + 0];
        const float yK = map_to[f * KBP + KBP - 1];
        const float dx = xK - x0;
        const float s  = (yK - y0) / dx;
        S[f]  = s;
        Bv[f] = fmaf(-x0, s, y0);
        affine = affine && (dx != 0.0f) && !isnan(s) && !isinf(s);
        #pragma unroll
        for (int k = 1; k < KBP; ++k) {
            const float xk = map_from[f * KBP + k];
            const float xp = map_from[f * KBP + k - 1];
            affine = affine && ((xk - xp) * dx > 0.0f);          // strictly monotone
            if (k < KBP - 1) {
                const float yk   = map_to[f * KBP + k];
                const float pred = fmaf(xk - x0, s, y0);
                affine = affine && (fabsf(yk - pred) <= 1e-5f);  // colinear
            }
        }
    }

    // float4 index i_c = blockIdx*1280 + c*256 + t; 1280==2, 256==1 (mod 3)
    // => i_c == 2*blockIdx + t + c (mod 3). Element e=4*i_c+j has
    // f = (i_c + j) % 3 = (m0 + c + j) % 3 with per-thread phase m0:
    const int m0 = (int)((2 * blockIdx.x + t) % 3);
    const long long base = (long long)blockIdx.x * (256 * CHUNKS) + t;

    const float4* __restrict__ in4  = reinterpret_cast<const float4*>(in);
    float4* __restrict__ out4 = reinterpret_cast<float4*>(out);

    if (affine) {
        // rotated coeffs: r -> table[(m0 + r) % 3]; 6 per-lane regs total
        float rs_[NF], rb_[NF];
        #pragma unroll
        for (int r = 0; r < NF; ++r) {
            rs_[r] = sel3(S[r],  S[(r + 1) % 3],  S[(r + 2) % 3],  m0);
            rb_[r] = sel3(Bv[r], Bv[(r + 1) % 3], Bv[(r + 2) % 3], m0);
        }
        float4 v[CHUNKS];
        #pragma unroll
        for (int c = 0; c < CHUNKS; ++c) {
            const long long ic = base + c * 256;
            if (ic < n4) v[c] = in4[ic];
        }
        #pragma unroll
        for (int c = 0; c < CHUNKS; ++c) {
            const long long ic = base + c * 256;
            if (ic < n4) {
                float4 o;
                o.x = fmaf(v[c].x, rs_[(c + 0) % 3], rb_[(c + 0) % 3]);
                o.y = fmaf(v[c].y, rs_[(c + 1) % 3], rb_[(c + 1) % 3]);
                o.z = fmaf(v[c].z, rs_[(c + 2) % 3], rb_[(c + 2) % 3]);
                o.w = fmaf(v[c].w, rs_[(c + 0) % 3], rb_[(c + 0) % 3]);
                out4[ic] = o;                    // <-- the R4 bug: was missing
            }
        }
    } else {
        // ---- generic fallback: LDS searchsorted + lerp (VGPR-light) ----
        #pragma unroll
        for (int c = 0; c < CHUNKS; ++c) {
            const long long ic = base + c * 256;
            if (ic >= n4) continue;
            const float4 x4 = in4[ic];
            float xv[4] = {x4.x, x4.y, x4.z, x4.w};
            float rv[4];
            #pragma unroll
            for (int j = 0; j < 4; ++j) {
                int f = m0 + c + j;
                f -= (f >= 3) ? 3 : 0;
                f -= (f >= 3) ? 3 : 0;
                f -= (f >= 3) ? 3 : 0;   // m0+c+j <= 9
                const float* xs = &s_from[f * KBP];
                const float* ys = &s_to[f * KBP];
                const float x = xv[j];
                int idx = 0;
                #pragma unroll
                for (int k = 1; k <= KBP - 2; ++k) idx += (x >= xs[k]) ? 1 : 0;
                const float x1 = xs[idx], x2 = xs[idx + 1];
                const float y1 = ys[idx], y2 = ys[idx + 1];
                rv[j] = y1 + (x - x1) * ((y2 - y1) / (x2 - x1));
            }
            out4[ic] = make_float4(rv[0], rv[1], rv[2], rv[3]);
        }
    }

    // tail (n_total % 4): at most 3 elements, generic scalar path
    const long long tail_start = n4 * 4;
    if (blockIdx.x == 0 && t < (int)(n_total - tail_start)) {
        const long long e = tail_start + t;
        const float x = in[e];
        const int f = (int)(e % 3);
        const float* xs = &s_from[f * KBP];
        const float* ys = &s_to[f * KBP];
        int idx = 0;
        #pragma unroll
        for (int k = 1; k <= KBP - 2; ++k) idx += (x >= xs[k]) ? 1 : 0;
        const float x1 = xs[idx], x2 = xs[idx + 1];
        const float y1 = ys[idx], y2 = ys[idx + 1];
        out[e] = y1 + (x - x1) * ((y2 - y1) / (x2 - x1));
    }
}

extern "C" void kernel_launch(void* const* d_in, const int* in_sizes, int n_in,
                              void* d_out, int out_size, void* d_ws, size_t ws_size,
                              hipStream_t stream) {
    const float* in       = (const float*)d_in[0];
    const float* map_from = (const float*)d_in[1];
    const float* map_to   = (const float*)d_in[2];
    float* out            = (float*)d_out;

    const long long n_total = (long long)in_sizes[0];  // 48,000,000
    const long long n4 = n_total / 4;                  // 12,000,000

    const int block = 256;
    const long long per_block = (long long)block * CHUNKS;       // 1280 float4s
    long long grid_ll = (n4 + per_block - 1) / per_block;        // 9375 exact cover
    if (grid_ll < 1) grid_ll = 1;
    const int grid = (int)grid_ll;

    FeatureScaling_42752104464652_kernel<<<grid, block, 0, stream>>>(
        in, map_from, map_to, out, n4, n_total);
}

// Round 6
// 63.940 us; speedup vs baseline: 1.9587x; 1.2251x over previous
//
#include <hip/hip_runtime.h>

// FeatureScaling: per-feature piecewise-linear interpolation.
// inputs [B=8, N=2e6, F=3] f32 (f innermost), map_from/map_to [F=3, K=17] f32.
//
// R1: LDS-pipe-bound (19 ds_read/elem, 122us). R2: stride-48B loads broke
// coalescing (153us). R3: register tables -> sel3 remat, VALU-bound (88us).
// R5: affine specialization, 1 FMA/elem, 78us @ 3.7 TB/s effective.
// R6: non-temporal stores — output is write-once; keep it OUT of L2/L3 so
// the 192 MB input stays L3-resident across replays (FETCH 96MB -> ~0).
//
// Affine specialization (runtime-verified, wave-uniform): if each feature's
// (map_from, map_to) breakpoints are colinear and map_from monotone, the
// piecewise-linear map incl. extrapolation is exactly y = S_f*x + B_f.
// Generic LDS-searchsorted fallback otherwise.

#define KBP 17
#define NF 3
#define CHUNKS 5   // float4s per thread, spaced blockDim apart; 12e6 = 9375*1280

typedef float f32x4 __attribute__((ext_vector_type(4)));

// m==0 ? a : m==1 ? b : c   (2x v_cndmask)
__device__ __forceinline__ float sel3(float a, float b, float c, int m) {
    float r = (m == 1) ? b : a;
    return (m == 2) ? c : r;
}

__global__ __launch_bounds__(256) void FeatureScaling_42752104464652_kernel(
    const float* __restrict__ in,
    const float* __restrict__ map_from,
    const float* __restrict__ map_to,
    float* __restrict__ out,
    long long n4, long long n_total)
{
    __shared__ float s_from[NF * KBP];
    __shared__ float s_to[NF * KBP];
    const int t = threadIdx.x;
    if (t < NF * KBP) {
        s_from[t] = map_from[t];
        s_to[t]   = map_to[t];
    }
    __syncthreads();

    // ---- wave-uniform affine (colinearity) check + coefficients ----
    float S[NF], Bv[NF];
    bool affine = true;
    #pragma unroll
    for (int f = 0; f < NF; ++f) {
        const float x0 = map_from[f * KBP + 0];
        const float xK = map_from[f * KBP + KBP - 1];
        const float y0 = map_to[f * KBP + 0];
        const float yK = map_to[f * KBP + KBP - 1];
        const float dx = xK - x0;
        const float s  = (yK - y0) / dx;
        S[f]  = s;
        Bv[f] = fmaf(-x0, s, y0);
        affine = affine && (dx != 0.0f) && !isnan(s) && !isinf(s);
        #pragma unroll
        for (int k = 1; k < KBP; ++k) {
            const float xk = map_from[f * KBP + k];
            const float xp = map_from[f * KBP + k - 1];
            affine = affine && ((xk - xp) * dx > 0.0f);          // strictly monotone
            if (k < KBP - 1) {
                const float yk   = map_to[f * KBP + k];
                const float pred = fmaf(xk - x0, s, y0);
                affine = affine && (fabsf(yk - pred) <= 1e-5f);  // colinear
            }
        }
    }

    // float4 index i_c = blockIdx*1280 + c*256 + t; 1280==2, 256==1 (mod 3)
    // => i_c == 2*blockIdx + t + c (mod 3). Element e=4*i_c+j has
    // f = (i_c + j) % 3 = (m0 + c + j) % 3 with per-thread phase m0:
    const int m0 = (int)((2 * blockIdx.x + t) % 3);
    const long long base = (long long)blockIdx.x * (256 * CHUNKS) + t;

    const f32x4* __restrict__ in4 = reinterpret_cast<const f32x4*>(in);
    f32x4* __restrict__ out4      = reinterpret_cast<f32x4*>(out);

    if (affine) {
        // rotated coeffs: r -> table[(m0 + r) % 3]; 6 per-lane regs total
        float rs_[NF], rb_[NF];
        #pragma unroll
        for (int r = 0; r < NF; ++r) {
            rs_[r] = sel3(S[r],  S[(r + 1) % 3],  S[(r + 2) % 3],  m0);
            rb_[r] = sel3(Bv[r], Bv[(r + 1) % 3], Bv[(r + 2) % 3], m0);
        }
        f32x4 v[CHUNKS];
        #pragma unroll
        for (int c = 0; c < CHUNKS; ++c) {
            const long long ic = base + c * 256;
            if (ic < n4) v[c] = in4[ic];
        }
        #pragma unroll
        for (int c = 0; c < CHUNKS; ++c) {
            const long long ic = base + c * 256;
            if (ic < n4) {
                f32x4 o;
                o.x = fmaf(v[c].x, rs_[(c + 0) % 3], rb_[(c + 0) % 3]);
                o.y = fmaf(v[c].y, rs_[(c + 1) % 3], rb_[(c + 1) % 3]);
                o.z = fmaf(v[c].z, rs_[(c + 2) % 3], rb_[(c + 2) % 3]);
                o.w = fmaf(v[c].w, rs_[(c + 0) % 3], rb_[(c + 0) % 3]);
                __builtin_nontemporal_store(o, &out4[ic]);   // stream, don't cache
            }
        }
    } else {
        // ---- generic fallback: LDS searchsorted + lerp (VGPR-light) ----
        #pragma unroll
        for (int c = 0; c < CHUNKS; ++c) {
            const long long ic = base + c * 256;
            if (ic >= n4) continue;
            const f32x4 x4 = in4[ic];
            float xv[4] = {x4.x, x4.y, x4.z, x4.w};
            float rv[4];
            #pragma unroll
            for (int j = 0; j < 4; ++j) {
                int f = m0 + c + j;
                f -= (f >= 3) ? 3 : 0;
                f -= (f >= 3) ? 3 : 0;
                f -= (f >= 3) ? 3 : 0;   // m0+c+j <= 9
                const float* xs = &s_from[f * KBP];
                const float* ys = &s_to[f * KBP];
                const float x = xv[j];
                int idx = 0;
                #pragma unroll
                for (int k = 1; k <= KBP - 2; ++k) idx += (x >= xs[k]) ? 1 : 0;
                const float x1 = xs[idx], x2 = xs[idx + 1];
                const float y1 = ys[idx], y2 = ys[idx + 1];
                rv[j] = y1 + (x - x1) * ((y2 - y1) / (x2 - x1));
            }
            f32x4 o; o.x = rv[0]; o.y = rv[1]; o.z = rv[2]; o.w = rv[3];
            __builtin_nontemporal_store(o, &out4[ic]);
        }
    }

    // tail (n_total % 4): at most 3 elements, generic scalar path
    const long long tail_start = n4 * 4;
    if (blockIdx.x == 0 && t < (int)(n_total - tail_start)) {
        const long long e = tail_start + t;
        const float x = in[e];
        const int f = (int)(e % 3);
        const float* xs = &s_from[f * KBP];
        const float* ys = &s_to[f * KBP];
        int idx = 0;
        #pragma unroll
        for (int k = 1; k <= KBP - 2; ++k) idx += (x >= xs[k]) ? 1 : 0;
        const float x1 = xs[idx], x2 = xs[idx + 1];
        const float y1 = ys[idx], y2 = ys[idx + 1];
        out[e] = y1 + (x - x1) * ((y2 - y1) / (x2 - x1));
    }
}

extern "C" void kernel_launch(void* const* d_in, const int* in_sizes, int n_in,
                              void* d_out, int out_size, void* d_ws, size_t ws_size,
                              hipStream_t stream) {
    const float* in       = (const float*)d_in[0];
    const float* map_from = (const float*)d_in[1];
    const float* map_to   = (const float*)d_in[2];
    float* out            = (float*)d_out;

    const long long n_total = (long long)in_sizes[0];  // 48,000,000
    const long long n4 = n_total / 4;                  // 12,000,000

    const int block = 256;
    const long long per_block = (long long)block * CHUNKS;       // 1280 float4s
    long long grid_ll = (n4 + per_block - 1) / per_block;        // 9375 exact cover
    if (grid_ll < 1) grid_ll = 1;
    const int grid = (int)grid_ll;

    FeatureScaling_42752104464652_kernel<<<grid, block, 0, stream>>>(
        in, map_from, map_to, out, n4, n_total);
}